// Round 7
// baseline (176.330 us; speedup 1.0000x reference)
//
#include <hip/hip_runtime.h>

typedef unsigned short us;
typedef __attribute__((ext_vector_type(8))) short short8;
typedef __attribute__((ext_vector_type(4))) float f32x4;

__device__ __forceinline__ us f2bf(float f) {
  unsigned int u = __builtin_bit_cast(unsigned int, f);
  u += 0x7fffu + ((u >> 16) & 1u);
  return (us)(u >> 16);
}

// ---- prep: entity k-split GEMM (256) + token cast (4096) + Wt transpose (256)
//      + zero the finish counters ----
__global__ __launch_bounds__(256) void prep_kernel(
    const float* __restrict__ token, us* __restrict__ tokb,
    const float* __restrict__ Wt, us* __restrict__ WtT,
    const float* __restrict__ entity, const float* __restrict__ We,
    float* __restrict__ epart, int* __restrict__ cnt) {
  __shared__ float tile[64][65];
  __shared__ float eS[16][128];
  const int bid = blockIdx.x, tid = threadIdx.x;
  if (bid == 0 && tid < 64) cnt[tid] = 0;
  if (bid < 256) {  // entity k-split partial GEMM, coalesced We reads
    int kc = bid & 7, nt = (bid >> 3) & 7, b = bid >> 6;
    int k0 = kc << 7, n0 = nt << 7;
#pragma unroll
    for (int p = 0; p < 2; ++p) {
      int idx = (p << 8) + tid;
      int r = idx >> 5, kk = (idx & 31) << 2;
      *(float4*)&eS[r][kk] = *(const float4*)&entity[(size_t)(((b << 4) + r) << 10) + k0 + kk];
    }
    __syncthreads();
    const int col = tid & 127, rh = tid >> 7;
    const float* wP = We + ((size_t)k0 << 10) + n0 + col;
    float acc[8] = {0.f, 0.f, 0.f, 0.f, 0.f, 0.f, 0.f, 0.f};
#pragma unroll 8
    for (int k = 0; k < 128; ++k) {
      float wv = wP[(size_t)k << 10];
#pragma unroll
      for (int r = 0; r < 8; ++r)
        acc[r] = fmaf(wv, eS[(rh << 3) + r][k], acc[r]);
    }
    float* op = epart + (((size_t)((kc << 6) + (b << 4) + (rh << 3))) << 10) + n0 + col;
#pragma unroll
    for (int r = 0; r < 8; ++r) op[(size_t)r << 10] = acc[r];
  } else if (bid < 4352) {  // token f32 -> bf16
    int q = (bid - 256) * 256 + tid;
    float4 v = ((const float4*)token)[q];
    ushort4 o;
    o.x = f2bf(v.x); o.y = f2bf(v.y); o.z = f2bf(v.z); o.w = f2bf(v.w);
    ((ushort4*)tokb)[q] = o;
  } else {  // Wt[k][n] -> WtT[n][k] bf16
    int tb = bid - 4352;
    int bx = (tb & 15) << 6, by = ((tb >> 4) & 15) << 6;
    int r0 = tid >> 4, c0 = (tid & 15) << 2;
#pragma unroll
    for (int p = 0; p < 4; ++p) {
      int r = p * 16 + r0;
      float4 v = *(const float4*)&Wt[(size_t)(by + r) * 1024 + bx + c0];
      tile[r][c0] = v.x; tile[r][c0 + 1] = v.y;
      tile[r][c0 + 2] = v.z; tile[r][c0 + 3] = v.w;
    }
    __syncthreads();
#pragma unroll
    for (int p = 0; p < 4; ++p) {
      int r = p * 16 + r0;
      ushort4 o;
      o.x = f2bf(tile[c0 + 0][r]); o.y = f2bf(tile[c0 + 1][r]);
      o.z = f2bf(tile[c0 + 2][r]); o.w = f2bf(tile[c0 + 3][r]);
      *(ushort4*)&WtT[(size_t)(bx + r) * 1024 + by + c0] = o;
    }
  }
}

// ---- main: NO-LDS token GEMM (C[h,t]) + fused relu-dot epilogue
//      + last-block finalize. grid (tt=64, mh=8): all mh for a tt share an XCD.
__global__ __launch_bounds__(256) void main_kernel(
    const us* __restrict__ tokb, const us* __restrict__ WtT,
    const float* __restrict__ epart, const float* __restrict__ be,
    const float* __restrict__ bt, const float* __restrict__ wp,
    const float* __restrict__ bp, const int* __restrict__ mask,
    float* __restrict__ partial, int* __restrict__ cnt,
    float* __restrict__ out) {
  __shared__ __attribute__((aligned(16))) float eL[16][132];
  __shared__ __attribute__((aligned(16))) float btL[128];
  __shared__ __attribute__((aligned(16))) float wpL[128];
  __shared__ float pp[2][64][9];
  __shared__ int doneFlag;
  const int tid = threadIdx.x;
  const int tt = blockIdx.x, mh = blockIdx.y;
  const int h0 = mh << 7, b = tt >> 4, t0 = (tt & 15) << 6;
  // phase 1: entity act = sum of 8 k-partials + be -> eL; bt, wp -> LDS
#pragma unroll
  for (int p = 0; p < 2; ++p) {
    int q = (p << 8) + tid;
    int er = q >> 5, ec = (q & 31) << 2;
    f32x4 s = *(const f32x4*)&be[h0 + ec];
#pragma unroll
    for (int kc = 0; kc < 8; ++kc)
      s += *(const f32x4*)&epart[(((size_t)((kc << 6) + (b << 4) + er)) << 10) + h0 + ec];
    *(f32x4*)&eL[er][ec] = s;
  }
  if (tid < 128) btL[tid] = bt[h0 + tid];
  else wpL[tid - 128] = wp[h0 + tid - 128];
  // ---- K-loop: direct 16B fragment loads, no LDS, no barriers ----
  const int lane = tid & 63, wm = (tid >> 7) & 1, wn = (tid >> 6) & 1;
  const int l16 = lane & 15, oct = lane >> 4;
  const us* aP[4];
  const us* bP[2];
#pragma unroll
  for (int i = 0; i < 4; ++i)
    aP[i] = WtT + (size_t)(h0 + (wm << 6) + (i << 4) + l16) * 1024 + (oct << 3);
#pragma unroll
  for (int j = 0; j < 2; ++j)
    bP[j] = tokb + (size_t)((b << 10) + t0 + (wn << 5) + (j << 4) + l16) * 1024 + (oct << 3);
  f32x4 acc[4][2] = {};
#pragma unroll 4
  for (int kt = 0; kt < 32; ++kt) {
    const int ko = kt << 5;
    short8 af[4], bfr[2];
#pragma unroll
    for (int i = 0; i < 4; ++i) af[i] = *(const short8*)(aP[i] + ko);
#pragma unroll
    for (int j = 0; j < 2; ++j) bfr[j] = *(const short8*)(bP[j] + ko);
#pragma unroll
    for (int i = 0; i < 4; ++i)
#pragma unroll
      for (int j = 0; j < 2; ++j)
        acc[i][j] = __builtin_amdgcn_mfma_f32_16x16x32_bf16(af[i], bfr[j], acc[i][j], 0, 0, 0);
  }
  __syncthreads();  // eL/btL/wpL ready (phase-1 overlapped with K-loop issue)
  // ---- fused epilogue: per e, p[t] = sum_h relu(acc + bt + e) * Wp ----
  f32x4 btq[4], wpq[4];
#pragma unroll
  for (int i = 0; i < 4; ++i) {
    int hb = (wm << 6) + (i << 4) + (oct << 2);
    btq[i] = *(const f32x4*)&btL[hb];
    wpq[i] = *(const f32x4*)&wpL[hb];
  }
#pragma unroll
  for (int i = 0; i < 4; ++i)
#pragma unroll
    for (int j = 0; j < 2; ++j) acc[i][j] += btq[i];
  for (int eh = 0; eh < 2; ++eh) {  // two halves of 8 entities
    __syncthreads();
#pragma unroll
    for (int e8 = 0; e8 < 8; ++e8) {
      int e = (eh << 3) + e8;
      f32x4 ev[4];
#pragma unroll
      for (int i = 0; i < 4; ++i)
        ev[i] = *(const f32x4*)&eL[e][(wm << 6) + (i << 4) + (oct << 2)];
      float pj[2] = {0.f, 0.f};
#pragma unroll
      for (int j = 0; j < 2; ++j)
#pragma unroll
        for (int i = 0; i < 4; ++i)
#pragma unroll
          for (int r = 0; r < 4; ++r)
            pj[j] = fmaf(fmaxf(acc[i][j][r] + ev[i][r], 0.f), wpq[i][r], pj[j]);
#pragma unroll
      for (int j = 0; j < 2; ++j) {
        pj[j] += __shfl_xor(pj[j], 16, 64);
        pj[j] += __shfl_xor(pj[j], 32, 64);
      }
      if (oct == 0) {
#pragma unroll
        for (int j = 0; j < 2; ++j) pp[wm][(wn << 5) + (j << 4) + l16][e8] = pj[j];
      }
    }
    __syncthreads();
#pragma unroll
    for (int q = 0; q < 2; ++q) {
      int flat = (q << 8) + tid;          // 0..511 = e8*64 + tl
      int e8 = flat >> 6, tl = flat & 63;
      float v = pp[0][tl][e8] + pp[1][tl][e8];
      partial[((size_t)mh << 16) +
              (size_t)((((b << 4) + (eh << 3) + e8) << 10) + t0 + tl)] = v;
    }
  }
  // ---- last-block-wins finalize for this tt column ----
  __threadfence();  // release partial writes device-wide
  if (tid == 0) {
    int old = atomicAdd(cnt + tt, 1);
    doneFlag = (old == 7);
  }
  __syncthreads();
  if (doneFlag) {
    __threadfence();  // acquire other blocks' partial writes
#pragma unroll
    for (int q = 0; q < 4; ++q) {
      int flat = (q << 8) + tid;          // 0..1023 = e*64 + tl
      int e = flat >> 6, tl = flat & 63;
      int t = t0 + tl;
      size_t oidx = ((size_t)((b << 4) + e) << 10) + t;
      float s = 0.f;
#pragma unroll
      for (int m = 0; m < 8; ++m) s += partial[((size_t)m << 16) + oidx];
      float cls = s + bp[0];
      if (mask[(b << 10) + t] == 0) cls = -10000.0f;
      out[oidx] = cls;
      out[65536 + oidx] = 1.0f / (1.0f + __expf(-cls));
    }
  }
}

extern "C" void kernel_launch(void* const* d_in, const int* in_sizes, int n_in,
                              void* d_out, int out_size, void* d_ws, size_t ws_size,
                              hipStream_t stream) {
  const float* token = (const float*)d_in[0];
  const float* entity = (const float*)d_in[1];
  const int* mask = (const int*)d_in[2];
  const float* Wt = (const float*)d_in[3];
  const float* bt = (const float*)d_in[4];
  const float* We = (const float*)d_in[5];
  const float* be = (const float*)d_in[6];
  const float* Wp = (const float*)d_in[7];
  const float* bp = (const float*)d_in[8];
  float* out = (float*)d_out;

  char* ws = (char*)d_ws;
  us* tokb = (us*)ws;                                   // 8 MB
  us* WtT = tokb + (size_t)4096 * 1024;                 // 2 MB
  float* epart = (float*)(WtT + (size_t)1024 * 1024);   // 2 MB [8][64][1024]
  float* partial = epart + (size_t)8 * 64 * 1024;       // 2 MB [8][4*16*1024]
  int* cnt = (int*)(partial + (size_t)8 * 64 * 1024);   // 256 B

  prep_kernel<<<4608, 256, 0, stream>>>(token, tokb, Wt, WtT, entity, We, epart, cnt);
  main_kernel<<<dim3(64, 8), 256, 0, stream>>>(tokb, WtT, epart, be, bt, Wp, bp, mask,
                                               partial, cnt, out);
}

// Round 9
// 152.950 us; speedup vs baseline: 1.1529x; 1.1529x over previous
//
#include <hip/hip_runtime.h>

typedef unsigned short us;
typedef __attribute__((ext_vector_type(8))) short short8;
typedef __attribute__((ext_vector_type(4))) float f32x4;

__device__ __forceinline__ us f2bf(float f) {
  unsigned int u = __builtin_bit_cast(unsigned int, f);
  u += 0x7fffu + ((u >> 16) & 1u);
  return (us)(u >> 16);
}
__device__ __forceinline__ unsigned int pk2(float lo, float hi) {
  return ((unsigned int)f2bf(hi) << 16) | (unsigned int)f2bf(lo);
}

// 16B-wide async global->LDS DMA. LDS dest = wave-uniform base + lane*16.
__device__ __forceinline__ void gload_lds16(const void* g, void* l) {
  __builtin_amdgcn_global_load_lds(
      (const __attribute__((address_space(1))) void*)g,
      (__attribute__((address_space(3))) void*)l, 16, 0, 0);
}

// ---- prep2: entity k-split GEMM (256) + Wt transpose (256) + cnt zero ----
__global__ __launch_bounds__(256) void prep2_kernel(
    const float* __restrict__ Wt, us* __restrict__ WtT,
    const float* __restrict__ entity, const float* __restrict__ We,
    float* __restrict__ epart, int* __restrict__ cnt) {
  __shared__ float tile[64][65];
  __shared__ float eS[16][128];
  const int bid = blockIdx.x, tid = threadIdx.x;
  if (bid == 0 && tid < 64) cnt[tid] = 0;
  if (bid < 256) {  // entity k-split partial GEMM, coalesced We reads
    int kc = bid & 7, nt = (bid >> 3) & 7, b = bid >> 6;
    int k0 = kc << 7, n0 = nt << 7;
#pragma unroll
    for (int p = 0; p < 2; ++p) {
      int idx = (p << 8) + tid;
      int r = idx >> 5, kk = (idx & 31) << 2;
      *(float4*)&eS[r][kk] = *(const float4*)&entity[(size_t)(((b << 4) + r) << 10) + k0 + kk];
    }
    __syncthreads();
    const int col = tid & 127, rh = tid >> 7;
    const float* wP = We + ((size_t)k0 << 10) + n0 + col;
    float acc[8] = {0.f, 0.f, 0.f, 0.f, 0.f, 0.f, 0.f, 0.f};
#pragma unroll 16
    for (int k = 0; k < 128; ++k) {
      float wv = wP[(size_t)k << 10];
#pragma unroll
      for (int r = 0; r < 8; ++r)
        acc[r] = fmaf(wv, eS[(rh << 3) + r][k], acc[r]);
    }
    float* op = epart + (((size_t)((kc << 6) + (b << 4) + (rh << 3))) << 10) + n0 + col;
#pragma unroll
    for (int r = 0; r < 8; ++r) op[(size_t)r << 10] = acc[r];
  } else {  // Wt[k][n] -> WtT[n][k] bf16
    int tb = bid - 256;
    int bx = (tb & 15) << 6, by = ((tb >> 4) & 15) << 6;
    int r0 = tid >> 4, c0 = (tid & 15) << 2;
#pragma unroll
    for (int p = 0; p < 4; ++p) {
      int r = p * 16 + r0;
      float4 v = *(const float4*)&Wt[(size_t)(by + r) * 1024 + bx + c0];
      tile[r][c0] = v.x; tile[r][c0 + 1] = v.y;
      tile[r][c0 + 2] = v.z; tile[r][c0 + 3] = v.w;
    }
    __syncthreads();
#pragma unroll
    for (int p = 0; p < 4; ++p) {
      int r = p * 16 + r0;
      ushort4 o;
      o.x = f2bf(tile[c0 + 0][r]); o.y = f2bf(tile[c0 + 1][r]);
      o.z = f2bf(tile[c0 + 2][r]); o.w = f2bf(tile[c0 + 3][r]);
      *(ushort4*)&WtT[(size_t)(bx + r) * 1024 + by + c0] = o;
    }
  }
}

// ---- main: token GEMM (C[h,t]) with in-kernel f32->bf16 Ts staging,
//      fused relu-dot epilogue + last-block finalize.
//      Ws: global_load_lds triple-buffer (R6-proven). Ts: float4 load ->
//      pack bf16 -> ds_write_b128, register-pipelined one iter ahead.
__global__ __launch_bounds__(256) void main_kernel(
    const float* __restrict__ token, const us* __restrict__ WtT,
    const float* __restrict__ epart, const float* __restrict__ be,
    const float* __restrict__ bt, const float* __restrict__ wp,
    const float* __restrict__ bp, const int* __restrict__ mask,
    float* __restrict__ partial, int* __restrict__ cnt,
    float* __restrict__ out) {
  __shared__ __attribute__((aligned(16))) us Ws[3][4096];   // [buf][128h x 32k] stride 32
  __shared__ __attribute__((aligned(16))) us Ts[3][2560];   // [buf][64t x stride 40]
  __shared__ __attribute__((aligned(16))) float eL[16][132];
  __shared__ __attribute__((aligned(16))) float btL[128];
  __shared__ __attribute__((aligned(16))) float wpL[128];
  __shared__ float pp[2][64][9];
  __shared__ int doneFlag;
  const int tid = threadIdx.x;
  const int tt = blockIdx.x, mh = blockIdx.y;
  const int h0 = mh << 7, b = tt >> 4, t0 = (tt & 15) << 6;
  // phase 1 first: its loads are OLDER than tile ops -> compiler waits for
  // them never drain the tile pipeline (in-order vmcnt retirement).
#pragma unroll
  for (int p = 0; p < 2; ++p) {
    int q = (p << 8) + tid;
    int er = q >> 5, ec = (q & 31) << 2;
    f32x4 s = *(const f32x4*)&be[h0 + ec];
#pragma unroll
    for (int kc = 0; kc < 8; ++kc)
      s += *(const f32x4*)&epart[(((size_t)((kc << 6) + (b << 4) + er)) << 10) + h0 + ec];
    *(f32x4*)&eL[er][ec] = s;
  }
  if (tid < 128) btL[tid] = bt[h0 + tid];
  else wpL[tid - 128] = wp[h0 + tid - 128];
  asm volatile("" ::: "memory");
  // staging setup
  const int row1 = tid >> 2;                 // 0..63
  const int c4 = tid & 3;
  const us* wP = WtT + (size_t)(h0 + row1) * 1024 + (c4 << 3);
  const float* tP = token + (size_t)((b << 10) + t0 + row1) * 1024 + (c4 << 3);
  const int w = tid >> 6;
  us* wB[3] = {&Ws[0][w * 512], &Ws[1][w * 512], &Ws[2][w * 512]};
  const int tsoff = row1 * 40 + (c4 << 3);   // shorts; *2B = 16B-aligned
  // prologue: Ws tiles 0..2 via DMA; token tiles 0,1 into regs; write Ts[0]
  gload_lds16(wP, wB[0]); gload_lds16(wP + 65536, wB[0] + 2048);
  gload_lds16(wP + 32, wB[1]); gload_lds16(wP + 65536 + 32, wB[1] + 2048);
  gload_lds16(wP + 64, wB[2]); gload_lds16(wP + 65536 + 64, wB[2] + 2048);
  float4 ca = *(const float4*)tP;
  float4 cb = *(const float4*)(tP + 4);
  float4 n1a = *(const float4*)(tP + 32);
  float4 n1b = *(const float4*)(tP + 36);
  {
    uint4 u;
    u.x = pk2(ca.x, ca.y); u.y = pk2(ca.z, ca.w);
    u.z = pk2(cb.x, cb.y); u.w = pk2(cb.z, cb.w);
    *(uint4*)&Ts[0][tsoff] = u;
  }
  ca = n1a; cb = n1b;
  const int lane = tid & 63, wm = (tid >> 7) & 1, wn = (tid >> 6) & 1;
  const int l16 = lane & 15, oct = lane >> 4, ko = oct << 3;
  int wfo[4], tfo[2];
#pragma unroll
  for (int i = 0; i < 4; ++i) wfo[i] = (((wm << 6) + (i << 4) + l16) << 5) + ko;
#pragma unroll
  for (int j = 0; j < 2; ++j) tfo[j] = ((wn << 5) + (j << 4) + l16) * 40 + ko;
  f32x4 acc[4][2] = {};
  // iter kt: wait lgkm0+vmcnt4 / barrier / MFMA buf kt%3 / barrier /
  //          DMA Ws tile kt+3 / load token tile kt+2 / write Ts tile kt+1
#define KBODY(KT, B0, B1)                                                     \
  {                                                                           \
    __builtin_amdgcn_s_waitcnt(0x0074); /* vmcnt(4) lgkmcnt(0) */             \
    __builtin_amdgcn_s_barrier();                                             \
    asm volatile("" ::: "memory");                                            \
    short8 af[4], bfr[2];                                                     \
    _Pragma("unroll") for (int i = 0; i < 4; ++i)                             \
        af[i] = *(const short8*)&Ws[B0][wfo[i]];                              \
    _Pragma("unroll") for (int j = 0; j < 2; ++j)                             \
        bfr[j] = *(const short8*)&Ts[B0][tfo[j]];                             \
    _Pragma("unroll") for (int i = 0; i < 4; ++i)                             \
        _Pragma("unroll") for (int j = 0; j < 2; ++j)                         \
            acc[i][j] = __builtin_amdgcn_mfma_f32_16x16x32_bf16(              \
                af[i], bfr[j], acc[i][j], 0, 0, 0);                           \
    asm volatile("" ::: "memory");                                            \
    __builtin_amdgcn_s_barrier();                                             \
    int nk3 = (KT) + 3; if (nk3 > 31) nk3 = 31; /* dummy keeps counts */      \
    gload_lds16(wP + (nk3 << 5), wB[B0]);                                     \
    gload_lds16(wP + 65536 + (nk3 << 5), wB[B0] + 2048);                      \
    int nk2 = (KT) + 2; if (nk2 > 31) nk2 = 31;                               \
    float4 na = *(const float4*)(tP + (nk2 << 5));                            \
    float4 nb = *(const float4*)(tP + (nk2 << 5) + 4);                        \
    uint4 u;                                                                  \
    u.x = pk2(ca.x, ca.y); u.y = pk2(ca.z, ca.w);                             \
    u.z = pk2(cb.x, cb.y); u.w = pk2(cb.z, cb.w);                             \
    *(uint4*)&Ts[B1][tsoff] = u;                                              \
    ca = na; cb = nb;                                                         \
  }
  for (int g = 0; g < 10; ++g) {
    const int kt = g * 3;
    KBODY(kt + 0, 0, 1);
    KBODY(kt + 1, 1, 2);
    KBODY(kt + 2, 2, 0);
  }
  KBODY(30, 0, 1);
  KBODY(31, 1, 2);
#undef KBODY
  // ---- fused epilogue: per e, p[t] = sum_h relu(acc + bt + e) * Wp ----
  f32x4 btq[4], wpq[4];
#pragma unroll
  for (int i = 0; i < 4; ++i) {
    int hb = (wm << 6) + (i << 4) + (oct << 2);
    btq[i] = *(const f32x4*)&btL[hb];
    wpq[i] = *(const f32x4*)&wpL[hb];
  }
#pragma unroll
  for (int i = 0; i < 4; ++i)
#pragma unroll
    for (int j = 0; j < 2; ++j) acc[i][j] += btq[i];
  for (int eh = 0; eh < 2; ++eh) {  // two halves of 8 entities
    __syncthreads();
#pragma unroll
    for (int e8 = 0; e8 < 8; ++e8) {
      int e = (eh << 3) + e8;
      f32x4 ev[4];
#pragma unroll
      for (int i = 0; i < 4; ++i)
        ev[i] = *(const f32x4*)&eL[e][(wm << 6) + (i << 4) + (oct << 2)];
      float pj[2] = {0.f, 0.f};
#pragma unroll
      for (int j = 0; j < 2; ++j)
#pragma unroll
        for (int i = 0; i < 4; ++i)
#pragma unroll
          for (int r = 0; r < 4; ++r)
            pj[j] = fmaf(fmaxf(acc[i][j][r] + ev[i][r], 0.f), wpq[i][r], pj[j]);
#pragma unroll
      for (int j = 0; j < 2; ++j) {
        pj[j] += __shfl_xor(pj[j], 16, 64);
        pj[j] += __shfl_xor(pj[j], 32, 64);
      }
      if (oct == 0) {
#pragma unroll
        for (int j = 0; j < 2; ++j) pp[wm][(wn << 5) + (j << 4) + l16][e8] = pj[j];
      }
    }
    __syncthreads();
#pragma unroll
    for (int q = 0; q < 2; ++q) {
      int flat = (q << 8) + tid;          // 0..511 = e8*64 + tl
      int e8 = flat >> 6, tl = flat & 63;
      float v = pp[0][tl][e8] + pp[1][tl][e8];
      partial[((size_t)mh << 16) +
              (size_t)((((b << 4) + (eh << 3) + e8) << 10) + t0 + tl)] = v;
    }
  }
  // ---- last-block-wins finalize for this tt column (R7-proven) ----
  __threadfence();
  if (tid == 0) {
    int old = atomicAdd(cnt + tt, 1);
    doneFlag = (old == 7);
  }
  __syncthreads();
  if (doneFlag) {
    __threadfence();
#pragma unroll
    for (int q = 0; q < 4; ++q) {
      int flat = (q << 8) + tid;          // 0..1023 = e*64 + tl
      int e = flat >> 6, tl = flat & 63;
      int t = t0 + tl;
      size_t oidx = ((size_t)((b << 4) + e) << 10) + t;
      float s = 0.f;
#pragma unroll
      for (int m = 0; m < 8; ++m) s += partial[((size_t)m << 16) + oidx];
      float cls = s + bp[0];
      if (mask[(b << 10) + t] == 0) cls = -10000.0f;
      out[oidx] = cls;
      out[65536 + oidx] = 1.0f / (1.0f + __expf(-cls));
    }
  }
}

extern "C" void kernel_launch(void* const* d_in, const int* in_sizes, int n_in,
                              void* d_out, int out_size, void* d_ws, size_t ws_size,
                              hipStream_t stream) {
  const float* token = (const float*)d_in[0];
  const float* entity = (const float*)d_in[1];
  const int* mask = (const int*)d_in[2];
  const float* Wt = (const float*)d_in[3];
  const float* bt = (const float*)d_in[4];
  const float* We = (const float*)d_in[5];
  const float* be = (const float*)d_in[6];
  const float* Wp = (const float*)d_in[7];
  const float* bp = (const float*)d_in[8];
  float* out = (float*)d_out;

  char* ws = (char*)d_ws;
  us* WtT = (us*)ws;                                    // 2 MB
  float* epart = (float*)(WtT + (size_t)1024 * 1024);   // 2 MB [8][64][1024]
  float* partial = epart + (size_t)8 * 64 * 1024;       // 2 MB [8][4*16*1024]
  int* cnt = (int*)(partial + (size_t)8 * 64 * 1024);   // 256 B

  prep2_kernel<<<512, 256, 0, stream>>>(Wt, WtT, entity, We, epart, cnt);
  main_kernel<<<dim3(64, 8), 256, 0, stream>>>(token, WtT, epart, be, bt, Wp, bp, mask,
                                               partial, cnt, out);
}